// Round 1
// baseline (1723.488 us; speedup 1.0000x reference)
//
#include <hip/hip_runtime.h>

#define DD 256
#define TT 4096
#define BB 32

// ======================= QKV GEMM (fp32 vector FMA) =======================
// Y = X @ W + b for the 3 projections (blockIdx.z picks q/k/v).
// 128x128 output tile, 256 threads, 8x8 per thread, K staged in 32-chunks.
__global__ __launch_bounds__(256, 2)
void qkv_gemm_kernel(const float* __restrict__ X,
                     const float* __restrict__ W0, const float* __restrict__ b0,
                     const float* __restrict__ W1, const float* __restrict__ b1,
                     const float* __restrict__ W2, const float* __restrict__ b2,
                     float* __restrict__ Y0, float* __restrict__ Y1, float* __restrict__ Y2)
{
    const float* Wm; const float* bias; float* Y;
    if (blockIdx.z == 0)      { Wm = W0; bias = b0; Y = Y0; }
    else if (blockIdx.z == 1) { Wm = W1; bias = b1; Y = Y1; }
    else                      { Wm = W2; bias = b2; Y = Y2; }

    __shared__ __align__(16) float As[32][132];  // [kc][m], pad 132 -> 4-bank skew
    __shared__ __align__(16) float Bs[32][132];  // [kc][n]

    const int tid = threadIdx.x;
    const int tx = tid & 15;   // 16 col-groups of 8
    const int ty = tid >> 4;   // 16 row-groups of 8
    const size_t row0 = (size_t)blockIdx.x * 128;
    const int col0 = blockIdx.y * 128;

    float acc[8][8];
    #pragma unroll
    for (int i = 0; i < 8; ++i)
        #pragma unroll
        for (int j = 0; j < 8; ++j) acc[i][j] = 0.f;

    for (int k0 = 0; k0 < 256; k0 += 32) {
        __syncthreads();
        #pragma unroll
        for (int it = 0; it < 16; ++it) {
            int idx = it * 256 + tid;
            int kc = idx & 31, m = idx >> 5;
            As[kc][m] = X[(row0 + (size_t)m) * 256 + (k0 + kc)];
        }
        #pragma unroll
        for (int it = 0; it < 16; ++it) {
            int idx = it * 256 + tid;
            int n = idx & 127, kc = idx >> 7;
            Bs[kc][n] = Wm[(size_t)(k0 + kc) * 256 + col0 + n];
        }
        __syncthreads();
        #pragma unroll 8
        for (int kc = 0; kc < 32; ++kc) {
            float4 a0 = *reinterpret_cast<const float4*>(&As[kc][ty * 8]);
            float4 a1 = *reinterpret_cast<const float4*>(&As[kc][ty * 8 + 4]);
            float4 c0 = *reinterpret_cast<const float4*>(&Bs[kc][tx * 8]);
            float4 c1 = *reinterpret_cast<const float4*>(&Bs[kc][tx * 8 + 4]);
            float ar[8] = {a0.x, a0.y, a0.z, a0.w, a1.x, a1.y, a1.z, a1.w};
            float br[8] = {c0.x, c0.y, c0.z, c0.w, c1.x, c1.y, c1.z, c1.w};
            #pragma unroll
            for (int i = 0; i < 8; ++i)
                #pragma unroll
                for (int j = 0; j < 8; ++j)
                    acc[i][j] = fmaf(ar[i], br[j], acc[i][j]);
        }
    }

    float bias_r[8];
    #pragma unroll
    for (int j = 0; j < 8; ++j) bias_r[j] = bias[col0 + tx * 8 + j];
    #pragma unroll
    for (int i = 0; i < 8; ++i) {
        size_t row = row0 + ty * 8 + i;
        float4 o0, o1;
        o0.x = acc[i][0] + bias_r[0]; o0.y = acc[i][1] + bias_r[1];
        o0.z = acc[i][2] + bias_r[2]; o0.w = acc[i][3] + bias_r[3];
        o1.x = acc[i][4] + bias_r[4]; o1.y = acc[i][5] + bias_r[5];
        o1.z = acc[i][6] + bias_r[6]; o1.w = acc[i][7] + bias_r[7];
        *reinterpret_cast<float4*>(&Y[row * 256 + col0 + tx * 8])     = o0;
        *reinterpret_cast<float4*>(&Y[row * 256 + col0 + tx * 8 + 4]) = o1;
    }
}

// ======================= fused pool + windowed attn + gelu + reduce ========
__device__ __forceinline__ float gelu_exact(float x) {
    return 0.5f * x * (1.0f + erff(x * 0.70710678118654752f));
}

// One wave per (window-chunk, head, batch). Lanes = the head's 64 features.
// Pooling (reflect-pad avg) done at load time; softmax in registers via
// butterfly shuffles; nearest-upsample+gelu+mean collapsed into per-token
// repeat-count weights, accumulated and atomicAdd'ed into acc[b][feature].
template<int KSIZE, int LEN, int NWIN, int WC>
__global__ __launch_bounds__(64)
void attn_kernel(const float* __restrict__ q, const float* __restrict__ k,
                 const float* __restrict__ v, float* __restrict__ acc)
{
    const int lane = threadIdx.x;                  // 0..63 = feature within head
    const int h = blockIdx.y;
    const int b = blockIdx.z;
    const int w0 = blockIdx.x * WC;
    const int wend = min(w0 + WC, NWIN);
    const size_t base = (size_t)b * TT * DD + h * 64 + lane;

    float accv = 0.f;
    for (int w = w0; w < wend; ++w) {
        float qr[4], kr[4], vr[4];
        #pragma unroll
        for (int r = 0; r < 4; ++r) {
            int p = w * 4 + r;
            float qv = 0.f, kv = 0.f, vv = 0.f;
            if (p < LEN) {
                if (KSIZE == 1) {
                    size_t o = base + (size_t)p * DD;
                    qv = q[o]; kv = k[o]; vv = v[o];
                } else if (KSIZE == 2) {
                    // reflect-pad 1: pooled[0]=(t0+t1)/2, interior=(t[2p-1]+t[2p])/2,
                    // pooled[L-1]=(t[T-2]+t[T-1])/2
                    int r0, r1;
                    if (p == 0)            { r0 = 0;      r1 = 1;      }
                    else if (p == LEN - 1) { r0 = TT - 2; r1 = TT - 1; }
                    else                   { r0 = 2*p - 1; r1 = 2*p;   }
                    size_t o0 = base + (size_t)r0 * DD, o1 = base + (size_t)r1 * DD;
                    qv = 0.5f * (q[o0] + q[o1]);
                    kv = 0.5f * (k[o0] + k[o1]);
                    vv = 0.5f * (v[o0] + v[o1]);
                } else { // KSIZE == 4, reflect-pad 2
                    int r0, r1, r2, r3;
                    if (p == 0)            { r0 = 2; r1 = 1; r2 = 0; r3 = 1; }
                    else if (p == LEN - 1) { r0 = TT - 3; r1 = TT - 2; r2 = TT - 2; r3 = TT - 1; }
                    else                   { r0 = 4*p - 2; r1 = 4*p - 1; r2 = 4*p; r3 = 4*p + 1; }
                    size_t o0 = base + (size_t)r0 * DD, o1 = base + (size_t)r1 * DD;
                    size_t o2 = base + (size_t)r2 * DD, o3 = base + (size_t)r3 * DD;
                    qv = 0.25f * (q[o0] + q[o1] + q[o2] + q[o3]);
                    kv = 0.25f * (k[o0] + k[o1] + k[o2] + k[o3]);
                    vv = 0.25f * (v[o0] + v[o1] + v[o2] + v[o3]);
                }
            }
            qr[r] = qv; kr[r] = kv; vr[r] = vv;
        }

        // scores S[i][j] = (q_i . k_j) / sqrt(64); butterfly-reduce over 64 lanes
        float P[4][4];
        #pragma unroll
        for (int i = 0; i < 4; ++i)
            #pragma unroll
            for (int j = 0; j < 4; ++j) {
                float s = qr[i] * kr[j];
                s += __shfl_xor(s, 1, 64);
                s += __shfl_xor(s, 2, 64);
                s += __shfl_xor(s, 4, 64);
                s += __shfl_xor(s, 8, 64);
                s += __shfl_xor(s, 16, 64);
                s += __shfl_xor(s, 32, 64);
                P[i][j] = s * 0.125f;
            }
        // softmax rows (padded cols carry score 0, included — matches reference)
        #pragma unroll
        for (int i = 0; i < 4; ++i) {
            float m = fmaxf(fmaxf(P[i][0], P[i][1]), fmaxf(P[i][2], P[i][3]));
            float e0 = __expf(P[i][0] - m), e1 = __expf(P[i][1] - m);
            float e2 = __expf(P[i][2] - m), e3 = __expf(P[i][3] - m);
            float inv = 1.0f / (e0 + e1 + e2 + e3);
            P[i][0] = e0 * inv; P[i][1] = e1 * inv; P[i][2] = e2 * inv; P[i][3] = e3 * inv;
        }
        // out = P @ V, gelu, weight by nearest-upsample repeat count
        #pragma unroll
        for (int i = 0; i < 4; ++i) {
            int p = w * 4 + i;
            if (p < LEN) {
                float o = P[i][0]*vr[0] + P[i][1]*vr[1] + P[i][2]*vr[2] + P[i][3]*vr[3];
                int c = ((p + 1) * TT + LEN - 1) / LEN - (p * TT + LEN - 1) / LEN;
                accv += (float)c * gelu_exact(o);
            }
        }
    }
    atomicAdd(&acc[b * DD + h * 64 + lane], accv);
}

// ======================= classifier head ===================================
// m = acc/4096; fused = m@Wp+bp; h = relu(fused@Wc1+bc1); out = h@Wc2+bc2
__global__ __launch_bounds__(256)
void classifier_kernel(const float* __restrict__ acc,
                       const float* __restrict__ Wp,  const float* __restrict__ bp,
                       const float* __restrict__ Wc1, const float* __restrict__ bc1,
                       const float* __restrict__ Wc2, const float* __restrict__ bc2,
                       float* __restrict__ out)
{
    const int b = blockIdx.x;
    const int d = threadIdx.x;
    __shared__ float sm[256], sf[256], sh[256];

    sm[d] = acc[b * 256 + d] * (1.0f / 4096.0f);
    __syncthreads();

    float s = bp[d];
    for (int kk = 0; kk < 256; ++kk) s = fmaf(sm[kk], Wp[kk * 256 + d], s);
    sf[d] = s;
    __syncthreads();

    s = bc1[d];
    for (int kk = 0; kk < 256; ++kk) s = fmaf(sf[kk], Wc1[kk * 256 + d], s);
    sh[d] = fmaxf(s, 0.0f);
    __syncthreads();

    if (d < 7) {
        s = bc2[d];
        for (int kk = 0; kk < 256; ++kk) s = fmaf(sh[kk], Wc2[kk * 7 + d], s);
        out[b * 7 + d] = s;
    }
}

// ======================= launch ============================================
extern "C" void kernel_launch(void* const* d_in, const int* in_sizes, int n_in,
                              void* d_out, int out_size, void* d_ws, size_t ws_size,
                              hipStream_t stream)
{
    const float* x   = (const float*)d_in[0];
    const float* Wq  = (const float*)d_in[1];
    const float* bq  = (const float*)d_in[2];
    const float* Wk  = (const float*)d_in[3];
    const float* bk  = (const float*)d_in[4];
    const float* Wv  = (const float*)d_in[5];
    const float* bv  = (const float*)d_in[6];
    const float* Wp  = (const float*)d_in[7];
    const float* bp  = (const float*)d_in[8];
    const float* Wc1 = (const float*)d_in[9];
    const float* bc1 = (const float*)d_in[10];
    const float* Wc2 = (const float*)d_in[11];
    const float* bc2 = (const float*)d_in[12];
    float* out = (float*)d_out;

    const size_t plane = (size_t)BB * TT * DD;   // 33,554,432 floats
    float* q   = (float*)d_ws;
    float* k   = q + plane;
    float* v   = k + plane;
    float* acc = v + plane;                       // 32*256 floats

    (void)hipMemsetAsync(acc, 0, BB * DD * sizeof(float), stream);

    // QKV projections: M=131072 (1024 x 128-row tiles), N=256 (2 tiles), z = q/k/v
    qkv_gemm_kernel<<<dim3(1024, 2, 3), 256, 0, stream>>>(
        x, Wq, bq, Wk, bk, Wv, bv, q, k, v);

    // scale 1: L=4096, nw=1024 ; scale 2 (pool 2): L=2049, nw=513 ; scale 3 (pool 4): L=1025, nw=257
    attn_kernel<1, 4096, 1024, 16><<<dim3(64, 4, BB), 64, 0, stream>>>(q, k, v, acc);
    attn_kernel<2, 2049,  513,  8><<<dim3(65, 4, BB), 64, 0, stream>>>(q, k, v, acc);
    attn_kernel<4, 1025,  257,  4><<<dim3(65, 4, BB), 64, 0, stream>>>(q, k, v, acc);

    classifier_kernel<<<dim3(BB), 256, 0, stream>>>(acc, Wp, bp, Wc1, bc1, Wc2, bc2, out);
}

// Round 2
// 563.827 us; speedup vs baseline: 3.0568x; 3.0568x over previous
//
#include <hip/hip_runtime.h>

#define DD 256
#define TT 4096
#define BB 32

typedef __attribute__((ext_vector_type(8))) short short8;   // 8 bf16 (4 VGPR)
typedef __attribute__((ext_vector_type(4))) float floatx4;  // MFMA acc

// ---------- bf16 helpers (RNE via bit twiddle) ----------
__device__ __forceinline__ unsigned short f2bf(float f) {
    unsigned u = __builtin_bit_cast(unsigned, f);
    unsigned r = u + 0x7FFFu + ((u >> 16) & 1u);
    return (unsigned short)(r >> 16);
}
__device__ __forceinline__ float bf2f(unsigned short h) {
    return __builtin_bit_cast(float, (unsigned)h << 16);
}
__device__ __forceinline__ float2 unpk(unsigned u) {
    float2 r;
    r.x = __builtin_bit_cast(float, u << 16);
    r.y = __builtin_bit_cast(float, u & 0xFFFF0000u);
    return r;
}

#define GLDS16(g, l)                                                        \
    __builtin_amdgcn_global_load_lds(                                       \
        (const __attribute__((address_space(1))) void*)(g),                 \
        (__attribute__((address_space(3))) void*)(l), 16, 0, 0)

// ======================= weight prep: split+transpose ======================
// Wt[z][half][n][k] bf16, z in {q,k,v}. hi = bf16(W), lo = bf16(W - hi).
__global__ void prep_w_kernel(const float* __restrict__ Wq,
                              const float* __restrict__ Wk,
                              const float* __restrict__ Wv,
                              unsigned short* __restrict__ Wt)
{
    const int z = blockIdx.y;
    const int k = blockIdx.x;      // 0..255
    const int n = threadIdx.x;     // 0..255
    const float* W = (z == 0) ? Wq : (z == 1) ? Wk : Wv;
    float w = W[k * 256 + n];
    unsigned short hi = f2bf(w);
    unsigned short lo = f2bf(w - bf2f(hi));
    size_t base = (size_t)z * 131072;
    Wt[base +         (size_t)n * 256 + k] = hi;
    Wt[base + 65536 + (size_t)n * 256 + k] = lo;
}

// ======================= QKV GEMM via bf16x3-split MFMA ====================
// C = xh@Wh + xh@Wl + xl@Wh (xl@Wl dropped, ~2^-16 rel).
// 128x128 tile, 256 thr (4 waves, each a 64x64 quadrant of 4x4 MFMA tiles).
// A staged fp32 via global_load_lds, split hi/lo at fragment build.
__global__ __launch_bounds__(256, 2)
void qkv_mfma_kernel(const float* __restrict__ X,
                     const unsigned short* __restrict__ Wt,
                     const float* __restrict__ bq, const float* __restrict__ bk,
                     const float* __restrict__ bv,
                     unsigned short* __restrict__ Q, unsigned short* __restrict__ Kp,
                     unsigned short* __restrict__ V)
{
    const int z = blockIdx.z;
    const unsigned short* Wz = Wt + (size_t)z * 131072;
    const float* bias = (z == 0) ? bq : (z == 1) ? bk : bv;
    unsigned short* Y = (z == 0) ? Q : (z == 1) ? Kp : V;

    __shared__ __align__(16) unsigned char smem[32768];
    float* Asm = (float*)smem;                       // [128][32] fp32, 16 KB
    unsigned short* Bsm = (unsigned short*)(smem + 16384); // [2][128][32] bf16, 16 KB

    const int tid = threadIdx.x;
    const int lane = tid & 63, wave = tid >> 6;
    const int wm = wave & 1, wn = wave >> 1;
    const int l15 = lane & 15, lq = lane >> 4;
    const int col0 = blockIdx.x * 128;
    const size_t row0 = (size_t)blockIdx.y * 128;

    floatx4 acc[4][4];
    #pragma unroll
    for (int i = 0; i < 4; ++i)
        #pragma unroll
        for (int j = 0; j < 4; ++j)
            acc[i][j] = (floatx4){0.f, 0.f, 0.f, 0.f};

    for (int k0 = 0; k0 < 256; k0 += 32) {
        __syncthreads();   // prior compute done before overwrite
        // A tile: [128][32] fp32 = 16 KB, 4 x 16B per thread
        #pragma unroll
        for (int it = 0; it < 4; ++it) {
            int flat = it * 256 + tid;
            int m = flat >> 3, ks = (flat & 7) * 4;
            GLDS16(X + (row0 + m) * 256 + k0 + ks, Asm + flat * 4);
        }
        // B tiles: [2][128][32] bf16, 2 x 2 x 16B per thread
        #pragma unroll
        for (int half = 0; half < 2; ++half)
            #pragma unroll
            for (int it = 0; it < 2; ++it) {
                int flat = it * 256 + tid;
                int n = flat >> 2, ks = (flat & 3) * 8;
                GLDS16(Wz + half * 65536 + (size_t)(col0 + n) * 256 + k0 + ks,
                       Bsm + half * 4096 + flat * 8);
            }
        __syncthreads();   // drains vmcnt before barrier

        // A fragments for this wave's 4 m-tiles: split hi/lo
        short8 ah[4], al[4];
        #pragma unroll
        for (int mt = 0; mt < 4; ++mt) {
            const float* ap = Asm + (wm * 64 + mt * 16 + l15) * 32 + lq * 8;
            float4 a0 = *(const float4*)ap;
            float4 a1 = *(const float4*)(ap + 4);
            float af[8] = {a0.x, a0.y, a0.z, a0.w, a1.x, a1.y, a1.z, a1.w};
            #pragma unroll
            for (int j = 0; j < 8; ++j) {
                unsigned short h = f2bf(af[j]);
                ah[mt][j] = (short)h;
                al[mt][j] = (short)f2bf(af[j] - bf2f(h));
            }
        }
        #pragma unroll
        for (int nt = 0; nt < 4; ++nt) {
            const unsigned short* bp = Bsm + (wn * 64 + nt * 16 + l15) * 32 + lq * 8;
            short8 bh = *(const short8*)bp;
            short8 bl = *(const short8*)(bp + 4096);
            #pragma unroll
            for (int mt = 0; mt < 4; ++mt) {
                acc[mt][nt] = __builtin_amdgcn_mfma_f32_16x16x32_bf16(ah[mt], bh, acc[mt][nt], 0, 0, 0);
                acc[mt][nt] = __builtin_amdgcn_mfma_f32_16x16x32_bf16(ah[mt], bl, acc[mt][nt], 0, 0, 0);
                acc[mt][nt] = __builtin_amdgcn_mfma_f32_16x16x32_bf16(al[mt], bh, acc[mt][nt], 0, 0, 0);
            }
        }
    }

    // ---- epilogue: bias + bf16 pack via per-wave LDS transpose ----
    __syncthreads();  // everyone done reading A/B before reuse
    unsigned short* Cs = (unsigned short*)(smem + wave * 8192); // [64][64] bf16
    #pragma unroll
    for (int nt = 0; nt < 4; ++nt) {
        float bv_ = bias[col0 + wn * 64 + nt * 16 + l15];
        #pragma unroll
        for (int mt = 0; mt < 4; ++mt)
            #pragma unroll
            for (int r = 0; r < 4; ++r) {
                int row = mt * 16 + lq * 4 + r;
                Cs[row * 64 + nt * 16 + l15] = f2bf(acc[mt][nt][r] + bv_);
            }
    }
    // coalesced 16B stores: 8 rows x 8 lanes per pass
    #pragma unroll
    for (int p = 0; p < 8; ++p) {
        int row = p * 8 + (lane >> 3);
        float4 d = *(const float4*)(Cs + row * 64 + (lane & 7) * 8);
        *(float4*)(Y + (row0 + wm * 64 + row) * 256 + col0 + wn * 64 + (lane & 7) * 8) = d;
    }
}

// ======================= fused pool + windowed attn + gelu + reduce ========
__device__ __forceinline__ float gelu_exact(float x) {
    return 0.5f * x * (1.0f + erff(x * 0.70710678118654752f));
}

// One wave per (window-chunk, head-pair, batch). Lane l handles head
// 2g+(l>>5), features (l&31)*2 and +1 (one packed dword per token per lane,
// 256 B contiguous per wave). Butterfly reduce within 32-lane halves.
template<int KSIZE, int LEN, int NWIN, int WC>
__global__ __launch_bounds__(64)
void attn_kernel(const unsigned short* __restrict__ qp,
                 const unsigned short* __restrict__ kp,
                 const unsigned short* __restrict__ vp,
                 float* __restrict__ acc)
{
    const int lane = threadIdx.x;
    const int g = blockIdx.y;       // head-pair
    const int b = blockIdx.z;
    const int w0 = blockIdx.x * WC;
    const int wend = min(w0 + WC, NWIN);
    const unsigned* qd = (const unsigned*)qp;
    const unsigned* kd = (const unsigned*)kp;
    const unsigned* vd = (const unsigned*)vp;
    const size_t base = (size_t)b * TT * 128 + g * 64 + lane; // dword units

    float2 accv = {0.f, 0.f};
    for (int w = w0; w < wend; ++w) {
        float2 qr[4], kr[4], vr[4];
        #pragma unroll
        for (int r = 0; r < 4; ++r) {
            int p = w * 4 + r;
            float2 qv = {0.f, 0.f}, kv = {0.f, 0.f}, vv = {0.f, 0.f};
            if (p < LEN) {
                if (KSIZE == 1) {
                    size_t o = base + (size_t)p * 128;
                    qv = unpk(qd[o]); kv = unpk(kd[o]); vv = unpk(vd[o]);
                } else if (KSIZE == 2) {
                    int r0, r1;
                    if (p == 0)            { r0 = 0;        r1 = 1;      }
                    else if (p == LEN - 1) { r0 = TT - 2;   r1 = TT - 1; }
                    else                   { r0 = 2 * p - 1; r1 = 2 * p; }
                    size_t o0 = base + (size_t)r0 * 128, o1 = base + (size_t)r1 * 128;
                    float2 a, c;
                    a = unpk(qd[o0]); c = unpk(qd[o1]); qv.x = 0.5f * (a.x + c.x); qv.y = 0.5f * (a.y + c.y);
                    a = unpk(kd[o0]); c = unpk(kd[o1]); kv.x = 0.5f * (a.x + c.x); kv.y = 0.5f * (a.y + c.y);
                    a = unpk(vd[o0]); c = unpk(vd[o1]); vv.x = 0.5f * (a.x + c.x); vv.y = 0.5f * (a.y + c.y);
                } else { // KSIZE == 4
                    int r0, r1, r2, r3;
                    if (p == 0)            { r0 = 2; r1 = 1; r2 = 0; r3 = 1; }
                    else if (p == LEN - 1) { r0 = TT - 3; r1 = TT - 2; r2 = TT - 2; r3 = TT - 1; }
                    else                   { r0 = 4*p - 2; r1 = 4*p - 1; r2 = 4*p; r3 = 4*p + 1; }
                    size_t o0 = base + (size_t)r0 * 128, o1 = base + (size_t)r1 * 128;
                    size_t o2 = base + (size_t)r2 * 128, o3 = base + (size_t)r3 * 128;
                    float2 a0, a1, a2, a3;
                    a0 = unpk(qd[o0]); a1 = unpk(qd[o1]); a2 = unpk(qd[o2]); a3 = unpk(qd[o3]);
                    qv.x = 0.25f * (a0.x + a1.x + a2.x + a3.x); qv.y = 0.25f * (a0.y + a1.y + a2.y + a3.y);
                    a0 = unpk(kd[o0]); a1 = unpk(kd[o1]); a2 = unpk(kd[o2]); a3 = unpk(kd[o3]);
                    kv.x = 0.25f * (a0.x + a1.x + a2.x + a3.x); kv.y = 0.25f * (a0.y + a1.y + a2.y + a3.y);
                    a0 = unpk(vd[o0]); a1 = unpk(vd[o1]); a2 = unpk(vd[o2]); a3 = unpk(vd[o3]);
                    vv.x = 0.25f * (a0.x + a1.x + a2.x + a3.x); vv.y = 0.25f * (a0.y + a1.y + a2.y + a3.y);
                }
            }
            qr[r] = qv; kr[r] = kv; vr[r] = vv;
        }

        // scores: dot over the head's 64 feats = 2/lane x 32-lane butterfly
        float P[4][4];
        #pragma unroll
        for (int i = 0; i < 4; ++i)
            #pragma unroll
            for (int j = 0; j < 4; ++j) {
                float s = qr[i].x * kr[j].x + qr[i].y * kr[j].y;
                s += __shfl_xor(s, 1, 64);
                s += __shfl_xor(s, 2, 64);
                s += __shfl_xor(s, 4, 64);
                s += __shfl_xor(s, 8, 64);
                s += __shfl_xor(s, 16, 64);
                P[i][j] = s * 0.125f;
            }
        #pragma unroll
        for (int i = 0; i < 4; ++i) {
            float m = fmaxf(fmaxf(P[i][0], P[i][1]), fmaxf(P[i][2], P[i][3]));
            float e0 = __expf(P[i][0] - m), e1 = __expf(P[i][1] - m);
            float e2 = __expf(P[i][2] - m), e3 = __expf(P[i][3] - m);
            float inv = 1.0f / (e0 + e1 + e2 + e3);
            P[i][0] = e0 * inv; P[i][1] = e1 * inv; P[i][2] = e2 * inv; P[i][3] = e3 * inv;
        }
        #pragma unroll
        for (int i = 0; i < 4; ++i) {
            int p = w * 4 + i;
            if (p < LEN) {
                float ox = P[i][0]*vr[0].x + P[i][1]*vr[1].x + P[i][2]*vr[2].x + P[i][3]*vr[3].x;
                float oy = P[i][0]*vr[0].y + P[i][1]*vr[1].y + P[i][2]*vr[2].y + P[i][3]*vr[3].y;
                int c = ((p + 1) * TT + LEN - 1) / LEN - (p * TT + LEN - 1) / LEN;
                accv.x += (float)c * gelu_exact(ox);
                accv.y += (float)c * gelu_exact(oy);
            }
        }
    }
    int fidx = (g * 2 + (lane >> 5)) * 64 + (lane & 31) * 2;
    atomicAdd(&acc[b * DD + fidx],     accv.x);
    atomicAdd(&acc[b * DD + fidx + 1], accv.y);
}

// ======================= classifier head ===================================
__global__ __launch_bounds__(256)
void classifier_kernel(const float* __restrict__ acc,
                       const float* __restrict__ Wp,  const float* __restrict__ bp,
                       const float* __restrict__ Wc1, const float* __restrict__ bc1,
                       const float* __restrict__ Wc2, const float* __restrict__ bc2,
                       float* __restrict__ out)
{
    const int b = blockIdx.x;
    const int d = threadIdx.x;
    __shared__ float sm[256], sf[256], sh[256];

    sm[d] = acc[b * 256 + d] * (1.0f / 4096.0f);
    __syncthreads();

    float s = bp[d];
    for (int kk = 0; kk < 256; ++kk) s = fmaf(sm[kk], Wp[kk * 256 + d], s);
    sf[d] = s;
    __syncthreads();

    s = bc1[d];
    for (int kk = 0; kk < 256; ++kk) s = fmaf(sf[kk], Wc1[kk * 256 + d], s);
    sh[d] = fmaxf(s, 0.0f);
    __syncthreads();

    if (d < 7) {
        s = bc2[d];
        for (int kk = 0; kk < 256; ++kk) s = fmaf(sh[kk], Wc2[kk * 7 + d], s);
        out[b * 7 + d] = s;
    }
}

// ======================= launch ============================================
extern "C" void kernel_launch(void* const* d_in, const int* in_sizes, int n_in,
                              void* d_out, int out_size, void* d_ws, size_t ws_size,
                              hipStream_t stream)
{
    const float* x   = (const float*)d_in[0];
    const float* Wq  = (const float*)d_in[1];
    const float* bq  = (const float*)d_in[2];
    const float* Wk  = (const float*)d_in[3];
    const float* bk  = (const float*)d_in[4];
    const float* Wv  = (const float*)d_in[5];
    const float* bv  = (const float*)d_in[6];
    const float* Wp  = (const float*)d_in[7];
    const float* bp  = (const float*)d_in[8];
    const float* Wc1 = (const float*)d_in[9];
    const float* bc1 = (const float*)d_in[10];
    const float* Wc2 = (const float*)d_in[11];
    const float* bc2 = (const float*)d_in[12];
    float* out = (float*)d_out;

    const size_t plane = (size_t)BB * TT * DD;       // 33,554,432 elems
    unsigned short* Q  = (unsigned short*)d_ws;       // bf16 planes
    unsigned short* K  = Q + plane;
    unsigned short* V  = K + plane;
    unsigned short* Wt = V + plane;                   // [3][2][256][256] bf16
    float* acc = (float*)(Wt + 3 * 131072);           // [32][256] fp32

    prep_w_kernel<<<dim3(256, 3), 256, 0, stream>>>(Wq, Wk, Wv, Wt);
    (void)hipMemsetAsync(acc, 0, BB * DD * sizeof(float), stream);

    // GEMM: grid x = col-tile (2) fastest for A-tile L2 reuse, y = row-tile, z = q/k/v
    qkv_mfma_kernel<<<dim3(2, 1024, 3), 256, 0, stream>>>(
        x, Wt, bq, bk, bv, Q, K, V);

    attn_kernel<1, 4096, 1024, 8><<<dim3(128, 2, BB), 64, 0, stream>>>(Q, K, V, acc);
    attn_kernel<2, 2049,  513, 8><<<dim3( 65, 2, BB), 64, 0, stream>>>(Q, K, V, acc);
    attn_kernel<4, 1025,  257, 4><<<dim3( 65, 2, BB), 64, 0, stream>>>(Q, K, V, acc);

    classifier_kernel<<<dim3(BB), 256, 0, stream>>>(acc, Wp, bp, Wc1, bc1, Wc2, bc2, out);
}